// Round 18
// baseline (771.879 us; speedup 1.0000x reference)
//
#include <hip/hip_runtime.h>
#include <hip/hip_bf16.h>

#define G_ 256
#define K_ 16
#define L_ 3
#define H_ 3
#define F_ 64
#define EMB_ 200
#define HID_ 256
#define N_ (G_*K_)

typedef __attribute__((ext_vector_type(8))) short short8;
typedef __attribute__((ext_vector_type(4))) float f32x4;

#define SELU_S 1.0507009873554804934193349852946f
#define SELU_SA (1.0507009873554804934193349852946f*1.6732632423543772848170429916717f)

__device__ __forceinline__ float selu_f(float x) {
  float e = __expf(x);
  float neg = fmaf(SELU_SA, e, -SELU_SA);
  float pos = SELU_S * x;
  return x > 0.f ? pos : neg;
}

__device__ __forceinline__ unsigned short f2bf(float x) {
  __hip_bfloat16 h = __float2bfloat16(x);
  return *reinterpret_cast<unsigned short*>(&h);
}

__device__ __forceinline__ unsigned int f2bf2(float a, float b) {
  float2 t; t.x = a; t.y = b;
  __hip_bfloat162 h = __float22bfloat162_rn(t);
  return *reinterpret_cast<unsigned int*>(&h);
}

__device__ __forceinline__ float bf2f(unsigned short u) {
  union { unsigned int i; float f; } v;
  v.i = ((unsigned int)u) << 16;
  return v.f;
}

// release-increment then acquire-spin until counter reaches target.
__device__ __forceinline__ void sync_counter(unsigned int* c, unsigned int target) {
  __threadfence();
  atomicAdd(c, 1u);                 // device scope on global
  long long guard = 0;
  while (__hip_atomic_load(c, __ATOMIC_ACQUIRE, __HIP_MEMORY_SCOPE_AGENT) < target) {
    __builtin_amdgcn_s_sleep(2);
    if (++guard > 200000000LL) break;   // safety valve: never hang the bench
  }
  __threadfence();
}

// ===========================================================================
// Persistent kernel: weight prep -> (spin barrier) -> init embed (LDS fea) ->
// 3 layers (per-graph 3-block atomic sync) -> crystal -> out. Grid 768x512.
// Co-residency: LDS 33.5KB (4 blk/CU), launch_bounds(512,6) caps VGPR<=85
// (>=3 blk/CU) -> aggregate capacity >= grid, spin barriers are safe.
// ===========================================================================
__global__ __launch_bounds__(512, 6) void roost_persist(
    const float* __restrict__ elem_weights, const float* __restrict__ elem_fea_in,
    const float* __restrict__ W_init, const float* __restrict__ b_init,
    const float* __restrict__ mg_W1, const float* __restrict__ mg_b1,
    const float* __restrict__ mg_W2, const float* __restrict__ mg_b2,
    const float* __restrict__ mm_W1, const float* __restrict__ mm_b1,
    const float* __restrict__ mm_W2, const float* __restrict__ mm_b2,
    const float* __restrict__ m_pow,
    const float* __restrict__ cg_W1, const float* __restrict__ cg_b1,
    const float* __restrict__ cg_W2, const float* __restrict__ cg_b2,
    const float* __restrict__ cm_W1, const float* __restrict__ cm_b1,
    const float* __restrict__ cm_W2, const float* __restrict__ cm_b2,
    const float* __restrict__ c_pow,
    unsigned int* cnt,                 // [0]=prep, [1..768]=layer, [769..1024]=crystal
    unsigned short* WcatT, unsigned short* W2mT,
    unsigned short* WcryT, unsigned short* W2cT,
    float* bias_e, float* bias_c,
    float* partE, float* partC, float* __restrict__ out) {
  __shared__ float feaL[16][64];
  __shared__ __align__(16) unsigned short feaS[16][72];
  __shared__ __align__(16) unsigned short PQs[16][520];
  __shared__ float bs[512];
  __shared__ float w2g[256];
  __shared__ float gred[240][2];
  __shared__ float gateA[240];
  __shared__ float accum[16][68];
  __shared__ float sumat[16];
  __shared__ float wp[16];

  int t = threadIdx.x;
  int bid = blockIdx.x;
  int g = bid / 3, h = bid - g*3;
  int g16 = g * 16;
  int w = t >> 6, lane = t & 63, mr = lane & 15, q = lane >> 4;
  unsigned int* cntL = cnt + 1;
  unsigned int* cntC = cnt + 1 + L_*G_;   // only need per-graph but stride G_ fine

  // ---- weight prep (grid-strided) ----
  {
    int gt = bid*512 + t, GT = gridDim.x*512;
    for (int idx = gt; idx < 9*1024*64; idx += GT) {
      int lh = idx >> 16, n = (idx >> 6) & 1023, k = idx & 63;
      const float* W = (n < 512) ? mg_W1 : mm_W1;
      int nn = n & 511;
      int r = (nn < 256) ? k : (64 + k);
      WcatT[idx] = f2bf(W[(size_t)lh*(2*F_*HID_) + r*HID_ + (nn & 255)]);
    }
    for (int idx = gt; idx < 9*64*256; idx += GT) {
      int lh = idx >> 14, f = (idx >> 8) & 63, k = idx & 255;
      W2mT[idx] = f2bf(mm_W2[(size_t)lh*(HID_*F_) + k*F_ + f]);
    }
    for (int idx = gt; idx < 1536*64; idx += GT) {
      int n = idx >> 6, k = idx & 63;
      int hh = n >> 9, r = n & 511;
      float v = (r < 256) ? cg_W1[(size_t)hh*F_*HID_ + k*HID_ + r]
                          : cm_W1[(size_t)hh*F_*HID_ + k*HID_ + (r - 256)];
      WcryT[idx] = f2bf(v);
    }
    for (int idx = gt; idx < 3*64*256; idx += GT) {
      int hh = idx >> 14, f = (idx >> 8) & 63, k = idx & 255;
      W2cT[idx] = f2bf(cm_W2[(size_t)hh*HID_*F_ + k*F_ + f]);
    }
    for (int idx = gt; idx < 9216 + 1536; idx += GT) {
      if (idx < 9216) {
        int l = idx / 3072, c = idx - l*3072;
        int hh = c >> 10, cc = c & 1023;
        int lh = l*H_ + hh;
        float v = 0.f;
        if (cc < 256) v = mg_b1[lh*HID_ + cc];
        else if (cc >= 512 && cc < 768) v = mm_b1[lh*HID_ + (cc - 512)];
        bias_e[idx] = v;
      } else {
        int c = idx - 9216;
        int hh = c >> 9, cc = c & 511;
        bias_c[c] = (cc < 256) ? cg_b1[hh*HID_ + cc] : cm_b1[hh*HID_ + (cc - 256)];
      }
    }
  }
  __syncthreads();

  // ---- init embed into feaL (overlaps other blocks' prep; uses raw inputs) --
  {
    float* rowbuf = (float*)PQs;    // 12.8 KB scratch inside 16.6 KB PQs
    for (int u = t; u < 16*EMB_; u += 512) {
      int n = u / EMB_, k = u - n*EMB_;
      rowbuf[n*EMB_ + k] = elem_fea_in[(size_t)(g16 + n)*EMB_ + k];
    }
    __syncthreads();
    for (int u = t; u < 1024; u += 512) {
      int n = u >> 6, j = u & 63;
      float v;
      if (j < F_-1) {
        float s = b_init[j];
        for (int k = 0; k < EMB_; ++k)
          s = fmaf(rowbuf[n*EMB_ + k], W_init[k*(F_-1) + j], s);
        v = s;
      } else {
        v = elem_weights[g16 + n];
      }
      feaL[n][j] = v;
    }
  }
  __syncthreads();
  if (t == 0) sync_counter(&cnt[0], gridDim.x);   // wait all prep done
  __syncthreads();

  // ---- layers ----
  for (int l = 0; l < L_; ++l) {
    int lh = l*H_ + h;
    const unsigned short* Wlh = WcatT + (size_t)lh*1024*64;
    const float* biaslh = bias_e + (size_t)l*3072 + h*1024;
    const unsigned short* W2lh = W2mT + (size_t)lh*64*256;

    // P0
    {
      int row = t >> 5, c2 = (t & 31) * 2;
      *(unsigned int*)&feaS[row][c2] = f2bf2(feaL[row][c2], feaL[row][c2+1]);
    }
    bs[t] = biaslh[t];
    if (t < 256) w2g[t] = mg_W2[lh*HID_ + t];
    #pragma unroll
    for (int s = 0; s < 3; ++s) {
      int idx = s*512 + t;
      if (idx < 16*68) ((float*)accum)[idx] = 0.f;
    }
    __syncthreads();

    // P1: gate-half PQ GEMM
    {
      int n0w = w * 64;
      short8 a0 = *(const short8*)&feaS[mr][q*8];
      short8 a1 = *(const short8*)&feaS[mr][32 + q*8];
      #pragma unroll
      for (int nt = 0; nt < 4; ++nt) {
        int n = n0w + nt*16 + mr;
        const unsigned short* bp = Wlh + (size_t)n*64 + q*8;
        short8 b0 = *(const short8*)bp;
        short8 b1 = *(const short8*)(bp + 32);
        f32x4 z = {0.f, 0.f, 0.f, 0.f};
        z = __builtin_amdgcn_mfma_f32_16x16x32_bf16(a0, b0, z, 0, 0, 0);
        z = __builtin_amdgcn_mfma_f32_16x16x32_bf16(a1, b1, z, 0, 0, 0);
        float bb = bs[n];
        #pragma unroll
        for (int r = 0; r < 4; ++r)
          PQs[q*4 + r][n] = f2bf(z[r] + bb);
      }
    }
    __syncthreads();

    // P2: gate dot + wp + msg bias reload
    {
      float nb = biaslh[512 + t];
      if (t < 480) {
        int e = t >> 1, half = t & 1;
        int i = e / 15, jj = e - i*15;
        int j = (jj < i) ? jj : jj + 1;
        float s = 0.f;
        #pragma unroll
        for (int u = 0; u < 16; ++u) {
          int c = half*8 + u*16;
          short8 pv = *(const short8*)&PQs[i][c];
          short8 qv = *(const short8*)&PQs[j][256 + c];
          #pragma unroll
          for (int r = 0; r < 8; ++r) {
            float hv = selu_f(bf2f((unsigned short)pv[r]) + bf2f((unsigned short)qv[r]));
            s = fmaf(hv, w2g[c + r], s);
          }
        }
        gred[e][half] = s;
      } else if (t < 496) {
        wp[t - 480] = __powf(elem_weights[g16 + (t - 480)], m_pow[lh]);
      }
      bs[t] = nb;
    }
    __syncthreads();

    // P3: msg-half PQ GEMM + softmax
    {
      int n0w = w * 64;
      short8 a0 = *(const short8*)&feaS[mr][q*8];
      short8 a1 = *(const short8*)&feaS[mr][32 + q*8];
      #pragma unroll
      for (int nt = 0; nt < 4; ++nt) {
        int n = n0w + nt*16 + mr;
        const unsigned short* bp = Wlh + (size_t)(512 + n)*64 + q*8;
        short8 b0 = *(const short8*)bp;
        short8 b1 = *(const short8*)(bp + 32);
        f32x4 z = {0.f, 0.f, 0.f, 0.f};
        z = __builtin_amdgcn_mfma_f32_16x16x32_bf16(a0, b0, z, 0, 0, 0);
        z = __builtin_amdgcn_mfma_f32_16x16x32_bf16(a1, b1, z, 0, 0, 0);
        float bb = bs[n];
        #pragma unroll
        for (int r = 0; r < 4; ++r)
          PQs[q*4 + r][n] = f2bf(z[r] + bb);
      }
    }
    if (t < 16) {
      int i = t;
      float b2v = mg_b2[lh];
      float gl[15];
      float m = -1e30f;
      #pragma unroll
      for (int jj = 0; jj < 15; ++jj) {
        float v = gred[i*15 + jj][0] + gred[i*15 + jj][1] + b2v;
        gl[jj] = v; m = fmaxf(m, v);
      }
      float den = 0.f;
      #pragma unroll
      for (int jj = 0; jj < 15; ++jj) {
        int j = (jj < i) ? jj : jj + 1;
        float x = wp[j] * __expf(gl[jj] - m);
        gl[jj] = x; den += x;
      }
      den += 1e-10f;
      float sa = 0.f;
      #pragma unroll
      for (int jj = 0; jj < 15; ++jj) {
        float a = gl[jj] / den; gateA[i*15 + jj] = a; sa += a;
      }
      sumat[i] = sa;
    }
    __syncthreads();

    // P4: msg MFMA + attn accum
    f32x4 acc[2][4];
    #pragma unroll
    for (int mi = 0; mi < 2; ++mi)
      #pragma unroll
      for (int nt = 0; nt < 4; ++nt) { f32x4 z = {0.f,0.f,0.f,0.f}; acc[mi][nt] = z; }
    int iL[2], jL[2];
    #pragma unroll
    for (int mi = 0; mi < 2; ++mi) {
      int mt = w*2 + mi; if (mt > 14) mt = 14;
      int e = mt*16 + mr;
      int i = e / 15, jj = e - i*15;
      iL[mi] = i; jL[mi] = (jj < i) ? jj : jj + 1;
    }
    for (int kc = 0; kc < 8; ++kc) {
      int k0 = kc*32 + q*8;
      short8 bfr[4];
      #pragma unroll
      for (int nt = 0; nt < 4; ++nt)
        bfr[nt] = *(const short8*)&W2lh[(size_t)(nt*16 + mr)*256 + k0];
      #pragma unroll
      for (int mi = 0; mi < 2; ++mi) {
        if (w*2 + mi < 15) {
          short8 pv = *(const short8*)&PQs[iL[mi]][k0];
          short8 qv = *(const short8*)&PQs[jL[mi]][256 + k0];
          float hv[8];
          #pragma unroll
          for (int r = 0; r < 8; ++r)
            hv[r] = selu_f(bf2f((unsigned short)pv[r]) + bf2f((unsigned short)qv[r]));
          unsigned int apk[4];
          #pragma unroll
          for (int r2 = 0; r2 < 4; ++r2) apk[r2] = f2bf2(hv[2*r2], hv[2*r2+1]);
          short8 a = *reinterpret_cast<short8*>(apk);
          #pragma unroll
          for (int nt = 0; nt < 4; ++nt)
            acc[mi][nt] = __builtin_amdgcn_mfma_f32_16x16x32_bf16(a, bfr[nt], acc[mi][nt], 0, 0, 0);
        }
      }
    }
    #pragma unroll
    for (int mi = 0; mi < 2; ++mi) {
      if (w*2 + mi < 15) {
        int ebase = (w*2 + mi)*16 + q*4;
        #pragma unroll
        for (int nt = 0; nt < 4; ++nt) {
          int f = nt*16 + mr;
          int icur = ebase / 15; float vsum = 0.f;
          #pragma unroll
          for (int r = 0; r < 4; ++r) {
            int e = ebase + r;
            int ie = e / 15;
            float v = acc[mi][nt][r] * gateA[e];
            if (ie != icur) { atomicAdd(&accum[icur][f], vsum); vsum = 0.f; icur = ie; }
            vsum += v;
          }
          atomicAdd(&accum[icur][f], vsum);
        }
      }
    }
    __syncthreads();

    // write head slab, per-graph 3-block sync, fold heads into feaL
    float* slab = partE + ((size_t)((l & 1)*3 + h)*G_ + g)*1024;
    #pragma unroll
    for (int s2 = 0; s2 < 2; ++s2) {
      int u = s2*512 + t;
      int i = u >> 6, f = u & 63;
      slab[u] = (accum[i][f] + mm_b2[lh*F_ + f]*sumat[i]) * (1.f/3.f);
    }
    __syncthreads();
    if (t == 0) sync_counter(&cntL[l*G_ + g], 3u);
    __syncthreads();
    const float* p0 = partE + ((size_t)((l & 1)*3 + 0)*G_ + g)*1024;
    const float* p1 = partE + ((size_t)((l & 1)*3 + 1)*G_ + g)*1024;
    const float* p2 = partE + ((size_t)((l & 1)*3 + 2)*G_ + g)*1024;
    #pragma unroll
    for (int s2 = 0; s2 < 2; ++s2) {
      int u = s2*512 + t;
      ((float*)feaL)[u] += p0[u] + p1[u] + p2[u];
    }
    __syncthreads();
  }

  // ---- crystal phase: block (g,h) computes head h ----
  {
    int row = t >> 5, c2 = (t & 31) * 2;
    *(unsigned int*)&feaS[row][c2] = f2bf2(feaL[row][c2], feaL[row][c2+1]);
  }
  bs[t] = bias_c[h*512 + t];
  __syncthreads();
  {
    int n0w = w * 64;
    short8 a0 = *(const short8*)&feaS[mr][q*8];
    short8 a1 = *(const short8*)&feaS[mr][32 + q*8];
    #pragma unroll
    for (int nt = 0; nt < 4; ++nt) {
      int n = n0w + nt*16 + mr;
      const unsigned short* bp = WcryT + (size_t)(h*512 + n)*64 + q*8;
      short8 b0 = *(const short8*)bp;
      short8 b1 = *(const short8*)(bp + 32);
      f32x4 z = {0.f, 0.f, 0.f, 0.f};
      z = __builtin_amdgcn_mfma_f32_16x16x32_bf16(a0, b0, z, 0, 0, 0);
      z = __builtin_amdgcn_mfma_f32_16x16x32_bf16(a1, b1, z, 0, 0, 0);
      float bb = bs[n];
      #pragma unroll
      for (int r = 0; r < 4; ++r)
        PQs[q*4 + r][n] = f2bf(z[r] + bb);
    }
  }
  __syncthreads();
  float (*gredc)[18] = (float(*)[18])gred;
  float* attnL = gateA;
  float* outg  = (float*)accum;
  if (t < 256) {                      // gate dot (last read of PQs gate half)
    int i = t >> 4, c0 = (t & 15) * 16;
    float s = 0.f;
    #pragma unroll
    for (int c = c0; c < c0+16; ++c)
      s = fmaf(selu_f(bf2f(PQs[i][c])), cg_W2[h*HID_ + c], s);
    gredc[i][t & 15] = s;
  } else if (t < 272) {
    wp[t - 256] = __powf(elem_weights[g16 + (t - 256)], c_pow[h]);
  }
  __syncthreads();
  if (t < 16) {
    float sg = 0.f;
    #pragma unroll
    for (int u2 = 0; u2 < 16; ++u2) sg += gredc[t][u2];
    gredc[t][16] = sg + cg_b2[h];
  }
  if (t < 64) outg[t] = 0.f;
  __syncthreads();
  if (t == 0) {
    float m = -1e30f;
    #pragma unroll
    for (int i = 0; i < 16; ++i) m = fmaxf(m, gredc[i][16]);
    float den = 0.f; float v[16];
    #pragma unroll
    for (int i = 0; i < 16; ++i) {
      float x = wp[i] * __expf(gredc[i][16] - m);
      v[i] = x; den += x;
    }
    den += 1e-10f;
    float sa = 0.f;
    #pragma unroll
    for (int i = 0; i < 16; ++i) { float a = v[i]/den; attnL[i] = a; sa += a; }
    sumat[0] = sa;
  }
  if (t >= 256) {                     // hid pack into dead PQs gate half
    int i = (t - 256) >> 4, c0 = ((t - 256) & 15) * 16;
    #pragma unroll
    for (int c = c0; c < c0+16; c += 2) {
      unsigned int pk = f2bf2(selu_f(bf2f(PQs[i][256 + c])),
                              selu_f(bf2f(PQs[i][256 + c + 1])));
      *(unsigned int*)&PQs[i][c] = pk;
    }
  }
  __syncthreads();
  if (w < 4) {
    f32x4 acc = {0.f, 0.f, 0.f, 0.f};
    #pragma unroll
    for (int kc = 0; kc < 8; ++kc) {
      short8 a = *(const short8*)&PQs[mr][kc*32 + q*8];
      short8 b = *(const short8*)&W2cT[((size_t)h*64 + w*16 + mr)*HID_ + kc*32 + q*8];
      acc = __builtin_amdgcn_mfma_f32_16x16x32_bf16(a, b, acc, 0, 0, 0);
    }
    float p = 0.f;
    #pragma unroll
    for (int r = 0; r < 4; ++r) p = fmaf(attnL[q*4+r], acc[r], p);
    atomicAdd(&outg[w*16+mr], p);
  }
  __syncthreads();
  if (t < 64)
    partC[((size_t)h*G_ + g)*64 + t] = outg[t] + cm_b2[h*F_ + t]*sumat[0];
  __syncthreads();
  if (t == 0) sync_counter(&cntC[g], 3u);
  __syncthreads();
  if (h == 0 && t < 64) {
    float v = partC[((size_t)0*G_ + g)*64 + t]
            + partC[((size_t)1*G_ + g)*64 + t]
            + partC[((size_t)2*G_ + g)*64 + t];
    out[(size_t)g*64 + t] = v * (1.f/(float)H_);
  }
}

extern "C" void kernel_launch(void* const* d_in, const int* in_sizes, int n_in,
                              void* d_out, int out_size, void* d_ws, size_t ws_size,
                              hipStream_t stream) {
  const float* elem_weights = (const float*)d_in[0];
  const float* elem_fea_in  = (const float*)d_in[1];
  const float* W_init = (const float*)d_in[2];
  const float* b_init = (const float*)d_in[3];
  const float* mg_W1  = (const float*)d_in[4];
  const float* mg_b1  = (const float*)d_in[5];
  const float* mg_W2  = (const float*)d_in[6];
  const float* mg_b2  = (const float*)d_in[7];
  const float* mm_W1  = (const float*)d_in[8];
  const float* mm_b1  = (const float*)d_in[9];
  const float* mm_W2  = (const float*)d_in[10];
  const float* mm_b2  = (const float*)d_in[11];
  const float* m_pow  = (const float*)d_in[12];
  const float* cg_W1  = (const float*)d_in[13];
  const float* cg_b1  = (const float*)d_in[14];
  const float* cg_W2  = (const float*)d_in[15];
  const float* cg_b2  = (const float*)d_in[16];
  const float* cm_W1  = (const float*)d_in[17];
  const float* cm_b1  = (const float*)d_in[18];
  const float* cm_W2  = (const float*)d_in[19];
  const float* cm_b2  = (const float*)d_in[20];
  const float* c_pow  = (const float*)d_in[21];
  float* out = (float*)d_out;

  // workspace layout (~28 MB): counters first (memset), then slabs + weights
  unsigned int* cnt = (unsigned int*)d_ws;                   // 1 + 3*G_ + G_
  float* partE  = (float*)(cnt + 1 + 3*G_ + G_);             // 2*3*256*1024
  float* partC  = partE + (size_t)2*3*G_*1024;               // 3*256*64
  float* bias_e = partC + (size_t)3*G_*64;                   // 9216
  float* bias_c = bias_e + 9216;                             // 1536
  unsigned short* WcatT = (unsigned short*)(bias_c + 1536);  // 9*1024*64
  unsigned short* W2mT  = WcatT + (size_t)9*1024*64;         // 9*64*256
  unsigned short* WcryT = W2mT  + (size_t)9*64*256;          // 1536*64
  unsigned short* W2cT  = WcryT + (size_t)1536*64;           // 3*64*256

  hipMemsetAsync(cnt, 0, (1 + 3*G_ + G_) * sizeof(unsigned int), stream);
  roost_persist<<<dim3(G_*H_), dim3(512), 0, stream>>>(
      elem_weights, elem_fea_in, W_init, b_init,
      mg_W1, mg_b1, mg_W2, mg_b2, mm_W1, mm_b1, mm_W2, mm_b2, m_pow,
      cg_W1, cg_b1, cg_W2, cg_b2, cm_W1, cm_b1, cm_W2, cm_b2, c_pow,
      cnt, WcatT, W2mT, WcryT, W2cT, bias_e, bias_c, partE, partC, out);
}

// Round 19
// 323.696 us; speedup vs baseline: 2.3846x; 2.3846x over previous
//
#include <hip/hip_runtime.h>
#include <hip/hip_bf16.h>

#define G_ 256
#define K_ 16
#define L_ 3
#define H_ 3
#define F_ 64
#define EMB_ 200
#define HID_ 256
#define N_ (G_*K_)

typedef __attribute__((ext_vector_type(8))) short short8;
typedef __attribute__((ext_vector_type(4))) float f32x4;

#define SELU_S 1.0507009873554804934193349852946f
#define SELU_SA (1.0507009873554804934193349852946f*1.6732632423543772848170429916717f)

__device__ __forceinline__ float selu_f(float x) {
  float e = __expf(x);
  float neg = fmaf(SELU_SA, e, -SELU_SA);
  float pos = SELU_S * x;
  return x > 0.f ? pos : neg;
}

__device__ __forceinline__ unsigned short f2bf(float x) {
  __hip_bfloat16 h = __float2bfloat16(x);
  return *reinterpret_cast<unsigned short*>(&h);
}

__device__ __forceinline__ unsigned int f2bf2(float a, float b) {
  float2 t; t.x = a; t.y = b;
  __hip_bfloat162 h = __float22bfloat162_rn(t);
  return *reinterpret_cast<unsigned int*>(&h);
}

__device__ __forceinline__ float bf2f(unsigned short u) {
  union { unsigned int i; float f; } v;
  v.i = ((unsigned int)u) << 16;
  return v.f;
}

// ---------------------------------------------------------------------------
// prep_init: grid 256 x 256. Block g: init-embed graph g into feaA; all
// blocks also grid-stride the bf16 weight transposes + bias folding.
// ---------------------------------------------------------------------------
__global__ __launch_bounds__(256) void prep_init(
    const float* __restrict__ elem_weights, const float* __restrict__ elem_fea_in,
    const float* __restrict__ W_init, const float* __restrict__ b_init,
    const float* __restrict__ mg_W1, const float* __restrict__ mm_W1,
    const float* __restrict__ mm_W2, const float* __restrict__ cg_W1,
    const float* __restrict__ cm_W1, const float* __restrict__ cm_W2,
    const float* __restrict__ mg_b1, const float* __restrict__ mm_b1,
    const float* __restrict__ cg_b1, const float* __restrict__ cm_b1,
    unsigned short* __restrict__ WcatT, unsigned short* __restrict__ W2mT,
    unsigned short* __restrict__ WcryT, unsigned short* __restrict__ W2cT,
    float* __restrict__ bias_e, float* __restrict__ bias_c,
    float* __restrict__ fea) {
  __shared__ float rowbuf[16*EMB_];
  int t = threadIdx.x;
  int g = blockIdx.x, g16 = g*16;

  // init embed for graph g
  for (int u = t; u < 16*EMB_; u += 256) {
    int n = u / EMB_, k = u - n*EMB_;
    rowbuf[n*EMB_ + k] = elem_fea_in[(size_t)(g16 + n)*EMB_ + k];
  }
  __syncthreads();
  for (int u = t; u < 1024; u += 256) {
    int n = u >> 6, j = u & 63;
    float v;
    if (j < F_-1) {
      float s = b_init[j];
      for (int k = 0; k < EMB_; ++k)
        s = fmaf(rowbuf[n*EMB_ + k], W_init[k*(F_-1) + j], s);
      v = s;
    } else {
      v = elem_weights[g16 + n];
    }
    fea[(size_t)(g16 + n)*F_ + j] = v;
  }

  // grid-strided weight prep
  int gt = g*256 + t, GT = G_*256;
  for (int idx = gt; idx < 9*1024*64; idx += GT) {
    int lh = idx >> 16, n = (idx >> 6) & 1023, k = idx & 63;
    const float* W = (n < 512) ? mg_W1 : mm_W1;
    int nn = n & 511;
    int r = (nn < 256) ? k : (64 + k);
    WcatT[idx] = f2bf(W[(size_t)lh*(2*F_*HID_) + r*HID_ + (nn & 255)]);
  }
  for (int idx = gt; idx < 9*64*256; idx += GT) {
    int lh = idx >> 14, f = (idx >> 8) & 63, k = idx & 255;
    W2mT[idx] = f2bf(mm_W2[(size_t)lh*(HID_*F_) + k*F_ + f]);
  }
  for (int idx = gt; idx < 1536*64; idx += GT) {
    int n = idx >> 6, k = idx & 63;
    int hh = n >> 9, r = n & 511;
    float v = (r < 256) ? cg_W1[(size_t)hh*F_*HID_ + k*HID_ + r]
                        : cm_W1[(size_t)hh*F_*HID_ + k*HID_ + (r - 256)];
    WcryT[idx] = f2bf(v);
  }
  for (int idx = gt; idx < 3*64*256; idx += GT) {
    int hh = idx >> 14, f = (idx >> 8) & 63, k = idx & 255;
    W2cT[idx] = f2bf(cm_W2[(size_t)hh*HID_*F_ + k*F_ + f]);
  }
  for (int idx = gt; idx < 9216 + 1536; idx += GT) {
    if (idx < 9216) {
      int l = idx / 3072, c = idx - l*3072;
      int hh = c >> 10, cc = c & 1023;
      int lh = l*H_ + hh;
      float v = 0.f;
      if (cc < 256) v = mg_b1[lh*HID_ + cc];
      else if (cc >= 512 && cc < 768) v = mm_b1[lh*HID_ + (cc - 512)];
      bias_e[idx] = v;
    } else {
      int c = idx - 9216;
      int hh = c >> 9, cc = c & 511;
      bias_c[c] = (cc < 256) ? cg_b1[hh*HID_ + cc] : cm_b1[hh*HID_ + (cc - 256)];
    }
  }
}

// ---------------------------------------------------------------------------
// Fused edge phase (R17 pipeline), slab-based head aggregation:
// P0: feaL = fea_in[g] (+ slab0+slab1+slab2 from previous layer, if any);
//     optionally store summed fea to fea_store (3 identical writes, benign).
// P1..P4 unchanged. End: write this head's slab (no atomics).
// ---------------------------------------------------------------------------
__global__ __launch_bounds__(512, 4) void edge_fused(
    const float* __restrict__ fea_in, const float* __restrict__ slabs_in,
    float* __restrict__ fea_store, float* __restrict__ slab_out,
    const unsigned short* __restrict__ WcatT, const float* __restrict__ bias_e,
    const unsigned short* __restrict__ W2T, const float* __restrict__ mg_W2,
    const float* __restrict__ mg_b2, const float* __restrict__ m_pow,
    const float* __restrict__ mm_b2, const float* __restrict__ wts, int l) {
  __shared__ __align__(16) unsigned short feaS[16][72];
  __shared__ __align__(16) unsigned short PQs[16][520];
  __shared__ float bs[512];
  __shared__ float w2g[256];
  __shared__ float gred[240][2];
  __shared__ float gateA[240];
  __shared__ float accum[16][68];
  __shared__ float sumat[16];
  __shared__ float wp[16];
  int t = threadIdx.x;
  int g = blockIdx.x, g16 = g * 16;
  int h = blockIdx.y, lh = l*H_ + h;
  const unsigned short* Wlh = WcatT + (size_t)lh*1024*64;
  const float* biaslh = bias_e + (size_t)l*3072 + h*1024;
  int w = t >> 6, lane = t & 63, mr = lane & 15, q = lane >> 4;

  // P0: feaL = fea_in (+ prev-layer slabs); stage bf16; optional store
  {
    int row = t >> 5, c2 = (t & 31) * 2;
    size_t o = (size_t)(g16 + row)*64 + c2;
    float2 fv = *(const float2*)&fea_in[o];
    if (slabs_in) {
      int so = row*64 + c2;
      const float* s0 = slabs_in + ((size_t)0*G_ + g)*1024;
      const float* s1 = slabs_in + ((size_t)1*G_ + g)*1024;
      const float* s2 = slabs_in + ((size_t)2*G_ + g)*1024;
      float2 a0 = *(const float2*)&s0[so];
      float2 a1 = *(const float2*)&s1[so];
      float2 a2 = *(const float2*)&s2[so];
      fv.x += a0.x + a1.x + a2.x;
      fv.y += a0.y + a1.y + a2.y;
      if (fea_store) *(float2*)&fea_store[o] = fv;
    }
    *(unsigned int*)&feaS[row][c2] = f2bf2(fv.x, fv.y);
  }
  bs[t] = biaslh[t];
  if (t < 256) w2g[t] = mg_W2[lh*HID_ + t];
  #pragma unroll
  for (int s = 0; s < 3; ++s) {
    int idx = s*512 + t;
    if (idx < 16*68) ((float*)accum)[idx] = 0.f;
  }
  __syncthreads();

  // P1: gate-half PQ GEMM (8 waves x 64 cols)
  {
    int n0w = w * 64;
    short8 a0 = *(const short8*)&feaS[mr][q*8];
    short8 a1 = *(const short8*)&feaS[mr][32 + q*8];
    #pragma unroll
    for (int nt = 0; nt < 4; ++nt) {
      int n = n0w + nt*16 + mr;
      const unsigned short* bp = Wlh + (size_t)n*64 + q*8;
      short8 b0 = *(const short8*)bp;
      short8 b1 = *(const short8*)(bp + 32);
      f32x4 z = {0.f, 0.f, 0.f, 0.f};
      z = __builtin_amdgcn_mfma_f32_16x16x32_bf16(a0, b0, z, 0, 0, 0);
      z = __builtin_amdgcn_mfma_f32_16x16x32_bf16(a1, b1, z, 0, 0, 0);
      float bb = bs[n];
      #pragma unroll
      for (int r = 0; r < 4; ++r)
        PQs[q*4 + r][n] = f2bf(z[r] + bb);
    }
  }
  __syncthreads();

  // P2: gate dot (480 thr) + wp precompute + msg bias reload
  {
    float nb = biaslh[512 + t];
    if (t < 480) {
      int e = t >> 1, half = t & 1;
      int i = e / 15, jj = e - i*15;
      int j = (jj < i) ? jj : jj + 1;
      float s = 0.f;
      #pragma unroll
      for (int u = 0; u < 16; ++u) {
        int c = half*8 + u*16;
        short8 pv = *(const short8*)&PQs[i][c];
        short8 qv = *(const short8*)&PQs[j][256 + c];
        #pragma unroll
        for (int r = 0; r < 8; ++r) {
          float hv = selu_f(bf2f((unsigned short)pv[r]) + bf2f((unsigned short)qv[r]));
          s = fmaf(hv, w2g[c + r], s);
        }
      }
      gred[e][half] = s;
    } else if (t < 496) {
      wp[t - 480] = __powf(wts[g16 + (t - 480)], m_pow[lh]);
    }
    bs[t] = nb;
  }
  __syncthreads();

  // P3: msg-half PQ GEMM (overwrite PQs) + softmax (t<16)
  {
    int n0w = w * 64;
    short8 a0 = *(const short8*)&feaS[mr][q*8];
    short8 a1 = *(const short8*)&feaS[mr][32 + q*8];
    #pragma unroll
    for (int nt = 0; nt < 4; ++nt) {
      int n = n0w + nt*16 + mr;
      const unsigned short* bp = Wlh + (size_t)(512 + n)*64 + q*8;
      short8 b0 = *(const short8*)bp;
      short8 b1 = *(const short8*)(bp + 32);
      f32x4 z = {0.f, 0.f, 0.f, 0.f};
      z = __builtin_amdgcn_mfma_f32_16x16x32_bf16(a0, b0, z, 0, 0, 0);
      z = __builtin_amdgcn_mfma_f32_16x16x32_bf16(a1, b1, z, 0, 0, 0);
      float bb = bs[n];
      #pragma unroll
      for (int r = 0; r < 4; ++r)
        PQs[q*4 + r][n] = f2bf(z[r] + bb);
    }
  }
  if (t < 16) {
    int i = t;
    float b2v = mg_b2[lh];
    float gl[15];
    float m = -1e30f;
    #pragma unroll
    for (int jj = 0; jj < 15; ++jj) {
      float v = gred[i*15 + jj][0] + gred[i*15 + jj][1] + b2v;
      gl[jj] = v; m = fmaxf(m, v);
    }
    float den = 0.f;
    #pragma unroll
    for (int jj = 0; jj < 15; ++jj) {
      int j = (jj < i) ? jj : jj + 1;
      float x = wp[j] * __expf(gl[jj] - m);
      gl[jj] = x; den += x;
    }
    den += 1e-10f;
    float sa = 0.f;
    #pragma unroll
    for (int jj = 0; jj < 15; ++jj) {
      float a = gl[jj] / den; gateA[i*15 + jj] = a; sa += a;
    }
    sumat[i] = sa;
  }
  __syncthreads();

  // P4: msg MFMA (15 m-tiles over 8 waves) + attn-weighted accum
  f32x4 acc[2][4];
  #pragma unroll
  for (int mi = 0; mi < 2; ++mi)
    #pragma unroll
    for (int nt = 0; nt < 4; ++nt) { f32x4 z = {0.f,0.f,0.f,0.f}; acc[mi][nt] = z; }
  int iL[2], jL[2];
  #pragma unroll
  for (int mi = 0; mi < 2; ++mi) {
    int mt = w*2 + mi; if (mt > 14) mt = 14;
    int e = mt*16 + mr;
    int i = e / 15, jj = e - i*15;
    iL[mi] = i; jL[mi] = (jj < i) ? jj : jj + 1;
  }
  const unsigned short* W2lh = W2T + (size_t)lh*64*256;

  for (int kc = 0; kc < 8; ++kc) {
    int k0 = kc*32 + q*8;
    short8 bfr[4];
    #pragma unroll
    for (int nt = 0; nt < 4; ++nt)
      bfr[nt] = *(const short8*)&W2lh[(size_t)(nt*16 + mr)*256 + k0];
    #pragma unroll
    for (int mi = 0; mi < 2; ++mi) {
      if (w*2 + mi < 15) {
        short8 pv = *(const short8*)&PQs[iL[mi]][k0];
        short8 qv = *(const short8*)&PQs[jL[mi]][256 + k0];
        float hv[8];
        #pragma unroll
        for (int r = 0; r < 8; ++r)
          hv[r] = selu_f(bf2f((unsigned short)pv[r]) + bf2f((unsigned short)qv[r]));
        unsigned int apk[4];
        #pragma unroll
        for (int r2 = 0; r2 < 4; ++r2) apk[r2] = f2bf2(hv[2*r2], hv[2*r2+1]);
        short8 a = *reinterpret_cast<short8*>(apk);
        #pragma unroll
        for (int nt = 0; nt < 4; ++nt)
          acc[mi][nt] = __builtin_amdgcn_mfma_f32_16x16x32_bf16(a, bfr[nt], acc[mi][nt], 0, 0, 0);
      }
    }
  }
  #pragma unroll
  for (int mi = 0; mi < 2; ++mi) {
    if (w*2 + mi < 15) {
      int ebase = (w*2 + mi)*16 + q*4;
      #pragma unroll
      for (int nt = 0; nt < 4; ++nt) {
        int f = nt*16 + mr;
        int icur = ebase / 15; float vsum = 0.f;
        #pragma unroll
        for (int r = 0; r < 4; ++r) {
          int e = ebase + r;
          int ie = e / 15;
          float v = acc[mi][nt][r] * gateA[e];
          if (ie != icur) { atomicAdd(&accum[icur][f], vsum); vsum = 0.f; icur = ie; }
          vsum += v;
        }
        atomicAdd(&accum[icur][f], vsum);
      }
    }
  }
  __syncthreads();
  // write this head's slab (full overwrite, LDS atomics only)
  float* slab = slab_out + ((size_t)h*G_ + g)*1024;
  #pragma unroll
  for (int s2 = 0; s2 < 2; ++s2) {
    int u = s2*512 + t;
    int i = u >> 6, f = u & 63;
    slab[u] = (accum[i][f] + mm_b2[lh*F_ + f]*sumat[i]) * (1.f/3.f);
  }
}

// ---------------------------------------------------------------------------
// Crystal phase: feaL = fea_in + last-layer slabs, then fused per-graph heads.
// ---------------------------------------------------------------------------
__global__ __launch_bounds__(256) void cry_fused(
    const float* __restrict__ fea_in, const float* __restrict__ slabs_in,
    const unsigned short* __restrict__ WcryT, const float* __restrict__ bias_c,
    const unsigned short* __restrict__ W2cT, const float* __restrict__ cg_W2,
    const float* __restrict__ cg_b2, const float* __restrict__ cm_b2,
    const float* __restrict__ c_pow, const float* __restrict__ wts,
    float* __restrict__ out) {
  __shared__ __align__(16) unsigned short feaS[16][72];
  __shared__ float PQh[16][520];
  __shared__ float bsc[512];
  __shared__ float gred[16][18];
  __shared__ float attnL[16];
  __shared__ float sumatS;
  __shared__ __align__(16) unsigned short hidc[16][264];
  __shared__ float outg[64];
  int t = threadIdx.x;
  int g = blockIdx.x, g16 = g*16;
  {
    int row = t >> 4, c4 = (t & 15) * 4;
    size_t o = (size_t)(g16 + row)*64 + c4;
    float4 fv = *(const float4*)&fea_in[o];
    int so = row*64 + c4;
    const float* s0 = slabs_in + ((size_t)0*G_ + g)*1024;
    const float* s1 = slabs_in + ((size_t)1*G_ + g)*1024;
    const float* s2 = slabs_in + ((size_t)2*G_ + g)*1024;
    float4 a0 = *(const float4*)&s0[so];
    float4 a1 = *(const float4*)&s1[so];
    float4 a2 = *(const float4*)&s2[so];
    fv.x += a0.x + a1.x + a2.x;
    fv.y += a0.y + a1.y + a2.y;
    fv.z += a0.z + a1.z + a2.z;
    fv.w += a0.w + a1.w + a2.w;
    *(unsigned int*)&feaS[row][c4]   = f2bf2(fv.x, fv.y);
    *(unsigned int*)&feaS[row][c4+2] = f2bf2(fv.z, fv.w);
  }
  if (t < 64) outg[t] = 0.f;
  int w = t >> 6, lane = t & 63, mr = lane & 15, q = lane >> 4;
  for (int h = 0; h < H_; ++h) {
    __syncthreads();
    bsc[t] = bias_c[h*512 + t];
    bsc[256 + t] = bias_c[h*512 + 256 + t];
    __syncthreads();
    {
      int n0w = w * 128;
      short8 a0 = *(const short8*)&feaS[mr][q*8];
      short8 a1 = *(const short8*)&feaS[mr][32 + q*8];
      #pragma unroll
      for (int nt = 0; nt < 8; ++nt) {
        int n = n0w + nt*16 + mr;
        const unsigned short* bp = WcryT + (size_t)(h*512 + n)*64 + q*8;
        short8 b0 = *(const short8*)bp;
        short8 b1 = *(const short8*)(bp + 32);
        f32x4 z = {0.f, 0.f, 0.f, 0.f};
        z = __builtin_amdgcn_mfma_f32_16x16x32_bf16(a0, b0, z, 0, 0, 0);
        z = __builtin_amdgcn_mfma_f32_16x16x32_bf16(a1, b1, z, 0, 0, 0);
        float bb = bsc[n];
        #pragma unroll
        for (int r = 0; r < 4; ++r)
          PQh[q*4 + r][n] = z[r] + bb;
      }
    }
    __syncthreads();
    {
      int i = t >> 4, c0 = (t & 15) * 16;
      float s = 0.f;
      #pragma unroll
      for (int c = c0; c < c0+16; ++c)
        s = fmaf(selu_f(PQh[i][c]), cg_W2[h*HID_ + c], s);
      gred[i][t & 15] = s;
    }
    __syncthreads();
    if (t < 16) {
      float sg = 0.f;
      #pragma unroll
      for (int u2 = 0; u2 < 16; ++u2) sg += gred[t][u2];
      gred[t][16] = sg + cg_b2[h];
    }
    __syncthreads();
    if (t == 0) {
      float pw = c_pow[h];
      float m = -1e30f;
      #pragma unroll
      for (int i = 0; i < 16; ++i) m = fmaxf(m, gred[i][16]);
      float den = 0.f; float v[16];
      #pragma unroll
      for (int i = 0; i < 16; ++i) {
        float x = __powf(wts[g16+i], pw) * __expf(gred[i][16] - m);
        v[i] = x; den += x;
      }
      den += 1e-10f;
      float sa = 0.f;
      #pragma unroll
      for (int i = 0; i < 16; ++i) { float a = v[i]/den; attnL[i] = a; sa += a; }
      sumatS = sa;
    }
    {
      int i = t >> 4, c0 = (t & 15) * 16;
      #pragma unroll
      for (int c = c0; c < c0+16; c += 2) {
        unsigned int pk = f2bf2(selu_f(PQh[i][256 + c]), selu_f(PQh[i][256 + c + 1]));
        *(unsigned int*)&hidc[i][c] = pk;
      }
    }
    __syncthreads();
    f32x4 acc = {0.f, 0.f, 0.f, 0.f};
    #pragma unroll
    for (int kc = 0; kc < 8; ++kc) {
      short8 a = *(const short8*)&hidc[mr][kc*32 + q*8];
      short8 b = *(const short8*)&W2cT[((size_t)h*64 + w*16 + mr)*HID_ + kc*32 + q*8];
      acc = __builtin_amdgcn_mfma_f32_16x16x32_bf16(a, b, acc, 0, 0, 0);
    }
    float p = 0.f;
    #pragma unroll
    for (int r = 0; r < 4; ++r) p = fmaf(attnL[q*4+r], acc[r], p);
    atomicAdd(&outg[w*16+mr], p);
    if (q == 0) atomicAdd(&outg[w*16+mr], cm_b2[h*F_ + w*16 + mr]*sumatS);
  }
  __syncthreads();
  if (t < 64) out[(size_t)g*64 + t] = outg[t] * (1.f/(float)H_);
}

extern "C" void kernel_launch(void* const* d_in, const int* in_sizes, int n_in,
                              void* d_out, int out_size, void* d_ws, size_t ws_size,
                              hipStream_t stream) {
  const float* elem_weights = (const float*)d_in[0];
  const float* elem_fea_in  = (const float*)d_in[1];
  const float* W_init = (const float*)d_in[2];
  const float* b_init = (const float*)d_in[3];
  const float* mg_W1  = (const float*)d_in[4];
  const float* mg_b1  = (const float*)d_in[5];
  const float* mg_W2  = (const float*)d_in[6];
  const float* mg_b2  = (const float*)d_in[7];
  const float* mm_W1  = (const float*)d_in[8];
  const float* mm_b1  = (const float*)d_in[9];
  const float* mm_W2  = (const float*)d_in[10];
  const float* mm_b2  = (const float*)d_in[11];
  const float* m_pow  = (const float*)d_in[12];
  const float* cg_W1  = (const float*)d_in[13];
  const float* cg_b1  = (const float*)d_in[14];
  const float* cg_W2  = (const float*)d_in[15];
  const float* cg_b2  = (const float*)d_in[16];
  const float* cm_W1  = (const float*)d_in[17];
  const float* cm_b1  = (const float*)d_in[18];
  const float* cm_W2  = (const float*)d_in[19];
  const float* cm_b2  = (const float*)d_in[20];
  const float* c_pow  = (const float*)d_in[21];
  float* out = (float*)d_out;

  // workspace (~16 MB)
  float* ws = (float*)d_ws;
  float* feaA  = ws;                                   // N*F
  float* feaB  = feaA + (size_t)N_*F_;                 // N*F
  float* partE = feaB + (size_t)N_*F_;                 // L*3*G*1024 (9 MB)
  float* bias_e = partE + (size_t)L_*3*G_*1024;        // 9216
  float* bias_c = bias_e + 9216;                       // 1536
  unsigned short* WcatT = (unsigned short*)(bias_c + 1536);  // 9*1024*64
  unsigned short* W2mT  = WcatT + (size_t)9*1024*64;         // 9*64*256
  unsigned short* WcryT = W2mT  + (size_t)9*64*256;          // 1536*64
  unsigned short* W2cT  = WcryT + (size_t)1536*64;           // 3*64*256

  prep_init<<<G_, 256, 0, stream>>>(
      elem_weights, elem_fea_in, W_init, b_init,
      mg_W1, mm_W1, mm_W2, cg_W1, cm_W1, cm_W2,
      mg_b1, mm_b1, cg_b1, cm_b1,
      WcatT, W2mT, WcryT, W2cT, bias_e, bias_c, feaA);

  // layer 0: in=feaA, no slabs, no store; out slabs_0
  edge_fused<<<dim3(G_, H_), 512, 0, stream>>>(
      feaA, nullptr, nullptr, partE + (size_t)0*3*G_*1024,
      WcatT, bias_e, W2mT, mg_W2, mg_b2, m_pow, mm_b2, elem_weights, 0);
  // layer 1: in=feaA+slabs_0 (store fea_1 to feaB); out slabs_1
  edge_fused<<<dim3(G_, H_), 512, 0, stream>>>(
      feaA, partE + (size_t)0*3*G_*1024, feaB, partE + (size_t)1*3*G_*1024,
      WcatT, bias_e, W2mT, mg_W2, mg_b2, m_pow, mm_b2, elem_weights, 1);
  // layer 2: in=feaB+slabs_1 (store fea_2 to feaA); out slabs_2
  edge_fused<<<dim3(G_, H_), 512, 0, stream>>>(
      feaB, partE + (size_t)1*3*G_*1024, feaA, partE + (size_t)2*3*G_*1024,
      WcatT, bias_e, W2mT, mg_W2, mg_b2, m_pow, mm_b2, elem_weights, 2);
  // crystal: in=feaA+slabs_2
  cry_fused<<<G_, 256, 0, stream>>>(
      feaA, partE + (size_t)2*3*G_*1024, WcryT, bias_c, W2cT,
      cg_W2, cg_b2, cm_b2, c_pow, elem_weights, out);
}